// Round 3
// baseline (508.288 us; speedup 1.0000x reference)
//
#include <hip/hip_runtime.h>

typedef __attribute__((ext_vector_type(8))) short bf16x8;
typedef __attribute__((ext_vector_type(4))) float f32x4;

// RNE float -> bf16
__device__ __forceinline__ unsigned short f2bf(float f) {
    union { float f; unsigned int u; } v; v.f = f;
    unsigned int r = v.u + 0x7FFFu + ((v.u >> 16) & 1u);
    return (unsigned short)(r >> 16);
}

// ---------------- counting-sort machinery ----------------
__global__ void hist_k(const int* __restrict__ dst, unsigned* __restrict__ counts, int E) {
    for (int i = blockIdx.x * blockDim.x + threadIdx.x; i < E; i += gridDim.x * blockDim.x)
        atomicAdd(&counts[dst[i]], 1u);
}

__global__ __launch_bounds__(1024)
void scan_k(const unsigned* __restrict__ counts, unsigned* __restrict__ cursor, int N) {
    __shared__ unsigned part[1024];
    const int t = threadIdx.x;
    const int chunk = (N + 1023) >> 10;
    const int lo = t * chunk, hi = min(lo + chunk, N);
    unsigned s = 0;
    for (int i = lo; i < hi; ++i) s += counts[i];
    part[t] = s;
    __syncthreads();
    for (int off = 1; off < 1024; off <<= 1) {
        unsigned v = (t >= off) ? part[t - off] : 0u;
        __syncthreads();
        part[t] += v;
        __syncthreads();
    }
    unsigned run = t ? part[t - 1] : 0u;
    for (int i = lo; i < hi; ++i) { cursor[i] = run; run += counts[i]; }
}

__global__ void scatter_k(const int* __restrict__ src, const int* __restrict__ dst,
                          unsigned* __restrict__ cursor, unsigned* __restrict__ eord,
                          int* __restrict__ esrc, int* __restrict__ edst, int E) {
    for (int i = blockIdx.x * blockDim.x + threadIdx.x; i < E; i += gridDim.x * blockDim.x) {
        int d = dst[i];
        unsigned p = atomicAdd(&cursor[d], 1u);
        eord[p] = (unsigned)i;
        if (esrc) { esrc[p] = src[i]; edst[p] = d; }
    }
}

// ------------- fused edge MLP + segmented scatter-reduce -------------
// Edges arrive sorted by dst. Swapped-operand MFMA (acc = mfma(W, data)) so a
// lane holds 4 consecutive features of one edge row. Y -> LDS [64][68] fp32,
// then 256 threads run-accumulate along sorted dst ids: ~runs*64 atomics/tile.
__global__ __launch_bounds__(256)
void edge_fused(const float* __restrict__ H, const float* __restrict__ Xe,
                const int* __restrict__ src, const int* __restrict__ dst,
                const unsigned* __restrict__ eord,
                const int* __restrict__ esrc, const int* __restrict__ edst,
                const float* __restrict__ W, const float* __restrict__ bias,
                float* __restrict__ Z, int E, int ntiles)
{
    __shared__ float smem[64 * 68];   // phase 1: bf16 A-tile (first 16KB); phase 2: Y fp32
    __shared__ int sdst[64];
    char* Ab = reinterpret_cast<char*>(smem);

    const int t = threadIdx.x, wave = t >> 6, lane = t & 63;
    const int lrow = lane & 15, lko = (lane >> 4) * 8, lko2 = lko * 2;

    // W fragments (A-operand): lane holds W[f*16+lrow][ks*32+lko+i]
    bf16x8 wfrag[4][4];
#pragma unroll
    for (int f = 0; f < 4; ++f)
#pragma unroll
        for (int ks = 0; ks < 4; ++ks) {
            const float* wp = W + (f * 16 + lrow) * 128 + ks * 32 + lko;
            bf16x8 v;
#pragma unroll
            for (int i = 0; i < 8; ++i) ((unsigned short*)&v)[i] = f2bf(wp[i]);
            wfrag[f][ks] = v;
        }
    const int fo = (lane >> 4) * 4;
    f32x4 bia[4];
#pragma unroll
    for (int f = 0; f < 4; ++f) bia[f] = *(const f32x4*)(bias + f * 16 + fo);

    const int el = t >> 2, q = t & 3, swz_w = (el & 7) << 4;

    for (int tile = blockIdx.x; tile < ntiles; tile += gridDim.x) {
        __syncthreads();  // prev iteration's smem/sdst reads done
        {
            const long long p = (long long)tile * 64 + el;
            const bool ok = p < (long long)E;
            int e = 0, sv = 0;
            if (ok) {
                e  = (int)eord[p];
                sv = esrc ? esrc[p] : src[e];
            }
            if (q == 0) sdst[el] = ok ? (edst ? edst[p] : dst[e]) : -1;
            const float* ap = H  + (long long)sv * 64;
            const float* bp = Xe + (long long)e * 64;
#pragma unroll
            for (int i = 0; i < 8; ++i) {
                const int c = q + 4 * i;
                float4 v = make_float4(0.f, 0.f, 0.f, 0.f);
                if (ok) v = (c < 16) ? *(const float4*)(ap + c * 4)
                                     : *(const float4*)(bp + (c - 16) * 4);
                unsigned lo32 = (unsigned)f2bf(v.x) | ((unsigned)f2bf(v.y) << 16);
                unsigned hi32 = (unsigned)f2bf(v.z) | ((unsigned)f2bf(v.w) << 16);
                *(uint2*)(Ab + ((el * 256 + c * 8) ^ swz_w)) = make_uint2(lo32, hi32);
            }
        }
        __syncthreads();

        f32x4 acc[4] = {{0,0,0,0},{0,0,0,0},{0,0,0,0},{0,0,0,0}};
        const int arl = wave * 16 + lrow, rbase = arl * 256, swz_r = (arl & 7) << 4;
#pragma unroll
        for (int ks = 0; ks < 4; ++ks) {
            bf16x8 a = *(const bf16x8*)(Ab + ((rbase + ks * 64 + lko2) ^ swz_r));
#pragma unroll
            for (int f = 0; f < 4; ++f)
                acc[f] = __builtin_amdgcn_mfma_f32_16x16x32_bf16(wfrag[f][ks], a, acc[f], 0, 0, 0);
        }
        __syncthreads();  // all waves done reading Ab; smem reusable

        // Y[row][feat] = relu(acc + bias); row = wave*16+(lane&15), feats f*16+fo+r
        {
            const int erow = wave * 16 + (lane & 15);
            float* yr = smem + erow * 68;
#pragma unroll
            for (int f = 0; f < 4; ++f) {
                f32x4 y;
#pragma unroll
                for (int r = 0; r < 4; ++r) y[r] = fmaxf(acc[f][r] + bia[f][r], 0.f);
                *(f32x4*)(yr + f * 16 + fo) = y;
            }
        }
        __syncthreads();

        // segmented reduce: thread owns feature f = t&63, rows r0..r0+15
        {
            const int f  = t & 63;
            const int r0 = (t >> 6) * 16;
            float a = 0.f;
            int cur = sdst[r0];
            for (int r = r0; r < r0 + 16; ++r) {
                int d = sdst[r];
                if (d != cur) {
                    if (cur >= 0) atomicAdd(Z + (long long)cur * 64 + f, a);
                    a = 0.f; cur = d;
                }
                a += smem[r * 68 + f];
            }
            if (cur >= 0) atomicAdd(Z + (long long)cur * 64 + f, a);
        }
    }
}

// ------------- generic tiled MLP (R1, known-good): node pass + fallback -------------
__global__ __launch_bounds__(256)
void gnn_mlp(const float* __restrict__ A, const float* __restrict__ B2,
             const int* __restrict__ gidx, const int* __restrict__ sidx,
             const float* __restrict__ W, const float* __restrict__ bias,
             float* __restrict__ out, int rows, int ntiles)
{
    __shared__ char Ab[64 * 128 * 2];
    const int t = threadIdx.x, wave = t >> 6, lane = t & 63;
    const int lrow = lane & 15, lko = (lane >> 4) * 8, lko2 = lko * 2;

    bf16x8 bfrag[4][4];
#pragma unroll
    for (int f = 0; f < 4; ++f)
#pragma unroll
        for (int ks = 0; ks < 4; ++ks) {
            const float* wp = W + (f * 16 + lrow) * 128 + ks * 32 + lko;
            bf16x8 v;
#pragma unroll
            for (int i = 0; i < 8; ++i) ((unsigned short*)&v)[i] = f2bf(wp[i]);
            bfrag[f][ks] = v;
        }
    float bia[4];
#pragma unroll
    for (int f = 0; f < 4; ++f) bia[f] = bias[f * 16 + lrow];

    const int el = t >> 2, q = t & 3, swz_w = (el & 7) << 4;

    for (int tile = blockIdx.x; tile < ntiles; tile += gridDim.x) {
        __syncthreads();
        {
            const long long e = (long long)tile * 64 + el;
            const bool ok = e < (long long)rows;
            long long arow = 0;
            if (ok) arow = gidx ? (long long)gidx[e] : e;
            const float* ap = A  + arow * 64;
            const float* bp = B2 + e * 64;
#pragma unroll
            for (int i = 0; i < 8; ++i) {
                const int c = q + 4 * i;
                float4 v = make_float4(0.f, 0.f, 0.f, 0.f);
                if (ok) v = (c < 16) ? *(const float4*)(ap + c * 4)
                                     : *(const float4*)(bp + (c - 16) * 4);
                unsigned lo32 = (unsigned)f2bf(v.x) | ((unsigned)f2bf(v.y) << 16);
                unsigned hi32 = (unsigned)f2bf(v.z) | ((unsigned)f2bf(v.w) << 16);
                *(uint2*)(Ab + ((el * 256 + c * 8) ^ swz_w)) = make_uint2(lo32, hi32);
            }
        }
        __syncthreads();

        f32x4 acc[4] = {{0,0,0,0},{0,0,0,0},{0,0,0,0},{0,0,0,0}};
        const int arl = wave * 16 + lrow, rbase = arl * 256, swz_r = (arl & 7) << 4;
#pragma unroll
        for (int ks = 0; ks < 4; ++ks) {
            bf16x8 a = *(const bf16x8*)(Ab + ((rbase + ks * 64 + lko2) ^ swz_r));
#pragma unroll
            for (int f = 0; f < 4; ++f)
                acc[f] = __builtin_amdgcn_mfma_f32_16x16x32_bf16(a, bfrag[f][ks], acc[f], 0, 0, 0);
        }

        const long long erow0 = (long long)tile * 64 + wave * 16 + (lane >> 4) * 4;
#pragma unroll
        for (int r = 0; r < 4; ++r) {
            const long long e = erow0 + r;
            if (e < (long long)rows) {
                if (sidx) {
                    const long long d = (long long)sidx[e] * 64;
#pragma unroll
                    for (int f = 0; f < 4; ++f)
                        atomicAdd(out + d + f * 16 + lrow, fmaxf(acc[f][r] + bia[f], 0.f));
                } else {
                    const long long o = e * 64;
#pragma unroll
                    for (int f = 0; f < 4; ++f)
                        out[o + f * 16 + lrow] = fmaxf(acc[f][r] + bia[f], 0.f);
                }
            }
        }
    }
}

extern "C" void kernel_launch(void* const* d_in, const int* in_sizes, int n_in,
                              void* d_out, int out_size, void* d_ws, size_t ws_size,
                              hipStream_t stream)
{
    const float* H   = (const float*)d_in[0];
    const float* Xe  = (const float*)d_in[1];
    const int*   idx = (const int*)d_in[2];
    const float* M_W = (const float*)d_in[3];
    const float* M_b = (const float*)d_in[4];
    const float* U_W = (const float*)d_in[5];
    const float* U_b = (const float*)d_in[6];
    float* Hn = (float*)d_out;

    const int n_nodes = out_size / 64;
    const int n_edges = in_sizes[1] / 64;
    const int* src = idx;
    const int* dst = idx + n_edges;

    char* ws = (char*)d_ws;
    float* Z = (float*)ws;
    size_t off = (size_t)n_nodes * 64 * sizeof(float);
    unsigned* counts = (unsigned*)(ws + off); off += (size_t)n_nodes * 4;
    unsigned* cursor = (unsigned*)(ws + off); off += (size_t)n_nodes * 4;
    unsigned* eord   = (unsigned*)(ws + off); off += (size_t)n_edges * 4;
    int* esrc = (int*)(ws + off); off += (size_t)n_edges * 4;
    int* edst = (int*)(ws + off); off += (size_t)n_edges * 4;
    const size_t need_full = off;
    const size_t need_min  = need_full - 2ull * (size_t)n_edges * 4;

    hipMemsetAsync(Z, 0, (size_t)n_nodes * 64 * sizeof(float), stream);

    const int etiles = (n_edges + 63) / 64;
    if (ws_size >= need_min) {
        const bool full = ws_size >= need_full;
        hipMemsetAsync(counts, 0, (size_t)n_nodes * 4, stream);
        hist_k<<<1024, 256, 0, stream>>>(dst, counts, n_edges);
        scan_k<<<1, 1024, 0, stream>>>(counts, cursor, n_nodes);
        scatter_k<<<1024, 256, 0, stream>>>(src, dst, cursor, eord,
                                            full ? esrc : nullptr,
                                            full ? edst : nullptr, n_edges);
        edge_fused<<<2048, 256, 0, stream>>>(H, Xe, src, dst, eord,
                                             full ? esrc : nullptr,
                                             full ? edst : nullptr,
                                             M_W, M_b, Z, n_edges, etiles);
    } else {
        gnn_mlp<<<2048, 256, 0, stream>>>(H, Xe, src, dst, M_W, M_b, Z, n_edges, etiles);
    }

    const int ntiles = (n_nodes + 63) / 64;
    gnn_mlp<<<ntiles, 256, 0, stream>>>(H, Z, nullptr, nullptr, U_W, U_b, Hn, n_nodes, ntiles);
}

// Round 4
// 487.219 us; speedup vs baseline: 1.0432x; 1.0432x over previous
//
#include <hip/hip_runtime.h>

typedef __attribute__((ext_vector_type(8))) short bf16x8;
typedef __attribute__((ext_vector_type(4))) float f32x4;

// RNE float -> bf16
__device__ __forceinline__ unsigned short f2bf(float f) {
    union { float f; unsigned int u; } v; v.f = f;
    unsigned int r = v.u + 0x7FFFu + ((v.u >> 16) & 1u);
    return (unsigned short)(r >> 16);
}

// ---------------- counting-sort machinery ----------------
__global__ void hist_k(const int* __restrict__ dst, unsigned* __restrict__ counts, int E) {
    for (int i = blockIdx.x * blockDim.x + threadIdx.x; i < E; i += gridDim.x * blockDim.x)
        atomicAdd(&counts[dst[i]], 1u);
}

__global__ __launch_bounds__(1024)
void scan_k(const unsigned* __restrict__ counts, unsigned* __restrict__ cursor, int N) {
    __shared__ unsigned part[1024];
    const int t = threadIdx.x;
    const int chunk = (N + 1023) >> 10;
    const int lo = t * chunk, hi = min(lo + chunk, N);
    unsigned s = 0;
    for (int i = lo; i < hi; ++i) s += counts[i];
    part[t] = s;
    __syncthreads();
    for (int off = 1; off < 1024; off <<= 1) {
        unsigned v = (t >= off) ? part[t - off] : 0u;
        __syncthreads();
        part[t] += v;
        __syncthreads();
    }
    unsigned run = t ? part[t - 1] : 0u;
    for (int i = lo; i < hi; ++i) { cursor[i] = run; run += counts[i]; }
}

// writes ONLY eord (src/dst re-read through L2 in the hot kernel)
__global__ void scatter_k(const int* __restrict__ dst, unsigned* __restrict__ cursor,
                          unsigned* __restrict__ eord, int E) {
    for (int i = blockIdx.x * blockDim.x + threadIdx.x; i < E; i += gridDim.x * blockDim.x) {
        unsigned p = atomicAdd(&cursor[dst[i]], 1u);
        eord[p] = (unsigned)i;
    }
}

// ------------- fused edge MLP + segmented scatter-reduce, 3-deep pipeline -------------
// Edges arrive dst-sorted via eord. Per iteration j (tile j consumed):
//   issue eord(j+3) -> src/dst(j+2) -> H/Xe data(j+1); each load has a full
//   iteration to land (T14 async-split generalized to depth 3).
__global__ __launch_bounds__(256)
void edge_fused(const float* __restrict__ H, const float* __restrict__ Xe,
                const int* __restrict__ src, const int* __restrict__ dst,
                const unsigned* __restrict__ eord,
                const float* __restrict__ W, const float* __restrict__ bias,
                float* __restrict__ Z, int E, int ntiles)
{
    __shared__ float smem[64 * 68];   // phase 1: bf16 A-tile (16KB); phase 2: Y fp32
    __shared__ int sdst[64];
    char* Ab = reinterpret_cast<char*>(smem);

    const int t = threadIdx.x, wave = t >> 6, lane = t & 63;
    const int lrow = lane & 15, lko = (lane >> 4) * 8, lko2 = lko * 2;

    // W fragments (A-operand, swapped-MFMA): lane holds W[f*16+lrow][ks*32+lko+i]
    bf16x8 wfrag[4][4];
#pragma unroll
    for (int f = 0; f < 4; ++f)
#pragma unroll
        for (int ks = 0; ks < 4; ++ks) {
            const float* wp = W + (f * 16 + lrow) * 128 + ks * 32 + lko;
            bf16x8 v;
#pragma unroll
            for (int i = 0; i < 8; ++i) ((unsigned short*)&v)[i] = f2bf(wp[i]);
            wfrag[f][ks] = v;
        }
    const int fo = (lane >> 4) * 4;
    f32x4 bia[4];
#pragma unroll
    for (int f = 0; f < 4; ++f) bia[f] = *(const f32x4*)(bias + f * 16 + fo);

    const int el = t >> 2, q = t & 3, swz_w = (el & 7) << 4;
    const long long step = (long long)gridDim.x * 64;

    // ---------- pipeline warmup ----------
    long long pbase = (long long)blockIdx.x * 64 + el;   // p for tile j=0, this row
    float4 dat[8];
    int dst0, e1, s1, d1;
    unsigned eo2;
    {
        const bool ok0 = pbase < E;
        int e0 = ok0 ? (int)eord[pbase] : 0;
        int s0 = ok0 ? src[e0] : 0;
        dst0   = ok0 ? dst[e0] : -1;
        const float* ap = H  + (long long)s0 * 64;
        const float* bp = Xe + (long long)e0 * 64;
#pragma unroll
        for (int i = 0; i < 8; ++i) {
            const int c = q + 4 * i;
            dat[i] = make_float4(0.f, 0.f, 0.f, 0.f);
            if (ok0) dat[i] = (c < 16) ? *(const float4*)(ap + c * 4)
                                       : *(const float4*)(bp + (c - 16) * 4);
        }
        const long long p1 = pbase + step;
        const bool ok1 = p1 < E;
        e1 = ok1 ? (int)eord[p1] : 0;
        s1 = ok1 ? src[e1] : 0;
        d1 = ok1 ? dst[e1] : -1;
        const long long p2 = p1 + step;
        eo2 = (p2 < E) ? eord[p2] : 0u;
    }

    for (int tile = blockIdx.x; tile < ntiles; tile += gridDim.x) {
        __syncthreads();  // prev iteration's smem/sdst reads done

        // ---- write A-tile(j) from registers, record dsts ----
        if (q == 0) sdst[el] = dst0;
#pragma unroll
        for (int i = 0; i < 8; ++i) {
            const int c = q + 4 * i;
            unsigned lo32 = (unsigned)f2bf(dat[i].x) | ((unsigned)f2bf(dat[i].y) << 16);
            unsigned hi32 = (unsigned)f2bf(dat[i].z) | ((unsigned)f2bf(dat[i].w) << 16);
            *(uint2*)(Ab + ((el * 256 + c * 8) ^ swz_w)) = make_uint2(lo32, hi32);
        }

        // ---- issue pipeline loads (land during compute of this & next tile) ----
        const long long b1 = pbase + step, b2 = b1 + step, b3 = b2 + step;
        const bool ok1 = b1 < E, ok2 = b2 < E, ok3 = b3 < E;
        {   // data(j+1) using indices landed last iteration
            const float* ap = H  + (long long)s1 * 64;
            const float* bp = Xe + (long long)e1 * 64;
#pragma unroll
            for (int i = 0; i < 8; ++i) {
                const int c = q + 4 * i;
                float4 v = make_float4(0.f, 0.f, 0.f, 0.f);
                if (ok1) v = (c < 16) ? *(const float4*)(ap + c * 4)
                                      : *(const float4*)(bp + (c - 16) * 4);
                dat[i] = v;
            }
        }
        const int s2t = ok2 ? src[(int)eo2] : 0;        // srcdst(j+2)
        const int d2t = ok2 ? dst[(int)eo2] : -1;
        const unsigned eo3 = ok3 ? eord[b3] : 0u;       // eord(j+3)

        __syncthreads();  // A-tile ready

        // ---- MFMA (swapped operands): wave w covers edge rows w*16..+15 ----
        f32x4 acc[4] = {{0,0,0,0},{0,0,0,0},{0,0,0,0},{0,0,0,0}};
        const int arl = wave * 16 + lrow, rbase = arl * 256, swz_r = (arl & 7) << 4;
#pragma unroll
        for (int ks = 0; ks < 4; ++ks) {
            bf16x8 a = *(const bf16x8*)(Ab + ((rbase + ks * 64 + lko2) ^ swz_r));
#pragma unroll
            for (int f = 0; f < 4; ++f)
                acc[f] = __builtin_amdgcn_mfma_f32_16x16x32_bf16(wfrag[f][ks], a, acc[f], 0, 0, 0);
        }
        __syncthreads();  // all waves done reading Ab; smem reusable for Y

        // ---- Y[row][feat] = relu(acc + bias) ----
        {
            const int erow = wave * 16 + (lane & 15);
            float* yr = smem + erow * 68;
#pragma unroll
            for (int f = 0; f < 4; ++f) {
                f32x4 y;
#pragma unroll
                for (int r = 0; r < 4; ++r) y[r] = fmaxf(acc[f][r] + bia[f][r], 0.f);
                *(f32x4*)(yr + f * 16 + fo) = y;
            }
        }
        __syncthreads();

        // ---- segmented reduce: wave w -> rows w*16..+15, feature = lane ----
        {
            const int f  = lane;
            const int r0 = wave * 16;
            float a = 0.f;
            int cur = sdst[r0];
            for (int r = r0; r < r0 + 16; ++r) {
                int d = sdst[r];
                if (d != cur) {
                    if (cur >= 0) atomicAdd(Z + (long long)cur * 64 + f, a);
                    a = 0.f; cur = d;
                }
                a += smem[r * 68 + f];
            }
            if (cur >= 0) atomicAdd(Z + (long long)cur * 64 + f, a);
        }

        // ---- rotate pipeline state ----
        dst0 = d1;
        e1 = (int)eo2; s1 = s2t; d1 = d2t;
        eo2 = eo3;
        pbase = b1;
    }
}

// ------------- generic tiled MLP (R1, known-good): node pass + fallback -------------
__global__ __launch_bounds__(256)
void gnn_mlp(const float* __restrict__ A, const float* __restrict__ B2,
             const int* __restrict__ gidx, const int* __restrict__ sidx,
             const float* __restrict__ W, const float* __restrict__ bias,
             float* __restrict__ out, int rows, int ntiles)
{
    __shared__ char Ab[64 * 128 * 2];
    const int t = threadIdx.x, wave = t >> 6, lane = t & 63;
    const int lrow = lane & 15, lko = (lane >> 4) * 8, lko2 = lko * 2;

    bf16x8 bfrag[4][4];
#pragma unroll
    for (int f = 0; f < 4; ++f)
#pragma unroll
        for (int ks = 0; ks < 4; ++ks) {
            const float* wp = W + (f * 16 + lrow) * 128 + ks * 32 + lko;
            bf16x8 v;
#pragma unroll
            for (int i = 0; i < 8; ++i) ((unsigned short*)&v)[i] = f2bf(wp[i]);
            bfrag[f][ks] = v;
        }
    float bia[4];
#pragma unroll
    for (int f = 0; f < 4; ++f) bia[f] = bias[f * 16 + lrow];

    const int el = t >> 2, q = t & 3, swz_w = (el & 7) << 4;

    for (int tile = blockIdx.x; tile < ntiles; tile += gridDim.x) {
        __syncthreads();
        {
            const long long e = (long long)tile * 64 + el;
            const bool ok = e < (long long)rows;
            long long arow = 0;
            if (ok) arow = gidx ? (long long)gidx[e] : e;
            const float* ap = A  + arow * 64;
            const float* bp = B2 + e * 64;
#pragma unroll
            for (int i = 0; i < 8; ++i) {
                const int c = q + 4 * i;
                float4 v = make_float4(0.f, 0.f, 0.f, 0.f);
                if (ok) v = (c < 16) ? *(const float4*)(ap + c * 4)
                                     : *(const float4*)(bp + (c - 16) * 4);
                unsigned lo32 = (unsigned)f2bf(v.x) | ((unsigned)f2bf(v.y) << 16);
                unsigned hi32 = (unsigned)f2bf(v.z) | ((unsigned)f2bf(v.w) << 16);
                *(uint2*)(Ab + ((el * 256 + c * 8) ^ swz_w)) = make_uint2(lo32, hi32);
            }
        }
        __syncthreads();

        f32x4 acc[4] = {{0,0,0,0},{0,0,0,0},{0,0,0,0},{0,0,0,0}};
        const int arl = wave * 16 + lrow, rbase = arl * 256, swz_r = (arl & 7) << 4;
#pragma unroll
        for (int ks = 0; ks < 4; ++ks) {
            bf16x8 a = *(const bf16x8*)(Ab + ((rbase + ks * 64 + lko2) ^ swz_r));
#pragma unroll
            for (int f = 0; f < 4; ++f)
                acc[f] = __builtin_amdgcn_mfma_f32_16x16x32_bf16(a, bfrag[f][ks], acc[f], 0, 0, 0);
        }

        const long long erow0 = (long long)tile * 64 + wave * 16 + (lane >> 4) * 4;
#pragma unroll
        for (int r = 0; r < 4; ++r) {
            const long long e = erow0 + r;
            if (e < (long long)rows) {
                if (sidx) {
                    const long long d = (long long)sidx[e] * 64;
#pragma unroll
                    for (int f = 0; f < 4; ++f)
                        atomicAdd(out + d + f * 16 + lrow, fmaxf(acc[f][r] + bia[f], 0.f));
                } else {
                    const long long o = e * 64;
#pragma unroll
                    for (int f = 0; f < 4; ++f)
                        out[o + f * 16 + lrow] = fmaxf(acc[f][r] + bia[f], 0.f);
                }
            }
        }
    }
}

extern "C" void kernel_launch(void* const* d_in, const int* in_sizes, int n_in,
                              void* d_out, int out_size, void* d_ws, size_t ws_size,
                              hipStream_t stream)
{
    const float* H   = (const float*)d_in[0];
    const float* Xe  = (const float*)d_in[1];
    const int*   idx = (const int*)d_in[2];
    const float* M_W = (const float*)d_in[3];
    const float* M_b = (const float*)d_in[4];
    const float* U_W = (const float*)d_in[5];
    const float* U_b = (const float*)d_in[6];
    float* Hn = (float*)d_out;

    const int n_nodes = out_size / 64;
    const int n_edges = in_sizes[1] / 64;
    const int* src = idx;
    const int* dst = idx + n_edges;

    char* ws = (char*)d_ws;
    float* Z = (float*)ws;
    size_t off = (size_t)n_nodes * 64 * sizeof(float);
    unsigned* counts = (unsigned*)(ws + off); off += (size_t)n_nodes * 4;
    unsigned* cursor = (unsigned*)(ws + off); off += (size_t)n_nodes * 4;
    unsigned* eord   = (unsigned*)(ws + off); off += (size_t)n_edges * 4;
    const size_t need = off;

    hipMemsetAsync(Z, 0, (size_t)n_nodes * 64 * sizeof(float), stream);

    const int etiles = (n_edges + 63) / 64;
    if (ws_size >= need) {
        hipMemsetAsync(counts, 0, (size_t)n_nodes * 4, stream);
        hist_k<<<1024, 256, 0, stream>>>(dst, counts, n_edges);
        scan_k<<<1, 1024, 0, stream>>>(counts, cursor, n_nodes);
        scatter_k<<<1024, 256, 0, stream>>>(dst, cursor, eord, n_edges);
        edge_fused<<<1024, 256, 0, stream>>>(H, Xe, src, dst, eord,
                                             M_W, M_b, Z, n_edges, etiles);
    } else {
        gnn_mlp<<<2048, 256, 0, stream>>>(H, Xe, src, dst, M_W, M_b, Z, n_edges, etiles);
    }

    const int ntiles = (n_nodes + 63) / 64;
    gnn_mlp<<<ntiles, 256, 0, stream>>>(H, Z, nullptr, nullptr, U_W, U_b, Hn, n_nodes, ntiles);
}